// Round 1
// baseline (6304.738 us; speedup 1.0000x reference)
//
#include <hip/hip_runtime.h>
#include <hip/hip_bf16.h>
#include <math.h>

// InstructPerceiverResampler on MI355X (gfx950).
// Round 0: bf16 MFMA T-mode GEMM (m97 structure: 128x128 tile, BK=32,
// global_load_lds w=16), materialized attention, fp32 residual stream.
//
// Workspace layout (~503 MiB): wT | biasf | xnorm | lat | lm | q | kv | Vt | SP | attn | ffh
// txtin/txth alias SP (preamble only).

typedef __attribute__((ext_vector_type(4))) float f32x4;
typedef __attribute__((ext_vector_type(8))) short bf16x8;
typedef unsigned int u32;

#define DEV __device__ __forceinline__

DEV float bf2f(short s){ union{u32 u; float f;} v; v.u = ((u32)(unsigned short)s) << 16; return v.f; }
DEV short f2bf(float f){
  union{float f; u32 u;} v; v.f = f;
  u32 r = (v.u + 0x7FFFu + ((v.u >> 16) & 1u)) >> 16;
  return (short)r;
}

// ---------------------------------------------------------------------------
// Generic batched T-mode GEMM: C[m,n] = scale * sum_k A[m,k]*B[n,k] (+bias)(+gelu)(+res)
// A: bf16 row-major (lda), B: bf16 row-major N x K (ldb).
// Batch z: zq=z/zdiv, zr=z%zdiv; base offsets via sA1/sA2 etc.
// Tile 128x128, BK=32, 256 threads (4 waves, 2x2 of 64x64).
// ---------------------------------------------------------------------------
template<int GELU, int BIAS, int RES, int OUTF32>
__global__ __launch_bounds__(256)
void gemm_t(const short* __restrict__ A, const short* __restrict__ B,
            void* __restrict__ C, const float* __restrict__ bias,
            const float* __restrict__ res,
            int K, int lda, int ldb, int ldc,
            int Mvalid, int NBmax, int Nwrite,
            int zdiv, long sA1, long sA2, long sB1, long sB2, long sC1, long sC2,
            float scale)
{
  __shared__ __align__(16) short As[128*32];
  __shared__ __align__(16) short Bs[128*32];

  int z = blockIdx.z;
  int zq = z / zdiv, zr = z - zq*zdiv;
  const short* Ab = A + zq*sA1 + zr*sA2;
  const short* Bb = B + zq*sB1 + zr*sB2;
  long cOff = zq*sC1 + zr*sC2;
  int m0 = blockIdx.y * 128;
  int n0 = blockIdx.x * 128;
  int tid = threadIdx.x;
  int lane = tid & 63;
  int w = tid >> 6;
  int wm = (w >> 1) * 64, wn = (w & 1) * 64;

  // staging: per wave, 2 chunks of 16 rows each for A and B. lane covers
  // row = base + lane/4, elem col = (lane&3)*8, 16B per lane (lds = base+lane*16).
  int sr = lane >> 2;
  int sc = (lane & 3) * 8;
  int ar0 = m0 + w*32 + sr;
  int br0 = n0 + w*32 + sr;

  f32x4 acc[4][4];
#pragma unroll
  for (int i=0;i<4;i++)
#pragma unroll
    for (int j=0;j<4;j++) acc[i][j] = (f32x4){0.f,0.f,0.f,0.f};

  for (int kb = 0; kb < K; kb += 32) {
#pragma unroll
    for (int i=0;i<2;i++){
      int ra = ar0 + i*16; if (ra > Mvalid-1) ra = Mvalid-1;
      const short* ga = Ab + (long)ra*lda + kb + sc;
      __builtin_amdgcn_global_load_lds(
          (const __attribute__((address_space(1))) u32*)ga,
          (__attribute__((address_space(3))) u32*)(As + (w*32 + i*16)*32), 16, 0, 0);
      int rb = br0 + i*16; if (rb > NBmax-1) rb = NBmax-1;
      const short* gb = Bb + (long)rb*ldb + kb + sc;
      __builtin_amdgcn_global_load_lds(
          (const __attribute__((address_space(1))) u32*)gb,
          (__attribute__((address_space(3))) u32*)(Bs + (w*32 + i*16)*32), 16, 0, 0);
    }
    __syncthreads();

    bf16x8 af[4], bfr[4];
    int kq = (lane >> 4) * 8;
    int rsel = lane & 15;
#pragma unroll
    for (int m=0;m<4;m++) af[m]  = *(const bf16x8*)&As[(wm + m*16 + rsel)*32 + kq];
#pragma unroll
    for (int n=0;n<4;n++) bfr[n] = *(const bf16x8*)&Bs[(wn + n*16 + rsel)*32 + kq];
#pragma unroll
    for (int m=0;m<4;m++)
#pragma unroll
      for (int n=0;n<4;n++)
        acc[m][n] = __builtin_amdgcn_mfma_f32_16x16x32_bf16(af[m], bfr[n], acc[m][n], 0, 0, 0);
    __syncthreads();
  }

  // epilogue: C/D layout col=lane&15, row=(lane>>4)*4+j (m89-verified)
  int cq = (lane >> 4) * 4;
  int csel = lane & 15;
#pragma unroll
  for (int m=0;m<4;m++){
#pragma unroll
    for (int n=0;n<4;n++){
#pragma unroll
      for (int j=0;j<4;j++){
        int gm = m0 + wm + m*16 + cq + j;
        int gn = n0 + wn + n*16 + csel;
        if (gm < Mvalid && gn < Nwrite){
          float v = acc[m][n][j] * scale;
          if (BIAS) v += bias[gn];
          if (GELU) v = 0.5f*v*(1.0f + erff(v*0.70710678118654752f));
          long off = cOff + (long)gm*ldc + gn;
          if (OUTF32){
            float rv = RES ? res[off] : 0.0f;
            ((float*)C)[off] = v + rv;
          } else {
            ((short*)C)[off] = f2bf(v);
          }
        }
      }
    }
  }
}

// ---------------------------------------------------------------------------
// transpose-convert: out[n*K+k] = bf16(in[k*N+n] * (s ? s[k] : 1))
// ---------------------------------------------------------------------------
__global__ __launch_bounds__(256)
void convT(const float* __restrict__ in, short* __restrict__ out,
           int K, int N, const float* __restrict__ s)
{
  __shared__ float tile[32][33];
  int kb = blockIdx.y*32, nb = blockIdx.x*32;
  int tx = threadIdx.x & 31, ty = threadIdx.x >> 5;
  for (int i = ty; i < 32; i += 8){
    int k = kb + i, n = nb + tx;
    float v = 0.f;
    if (k < K && n < N){ v = in[(long)k*N + n]; if (s) v *= s[k]; }
    tile[i][tx] = v;
  }
  __syncthreads();
  for (int i = ty; i < 32; i += 8){
    int n = nb + i, k = kb + tx;
    if (n < N && k < K) out[(long)n*K + k] = f2bf(tile[tx][i]);
  }
}

// biasf[n] = sum_k bvec[k] * W[k*3072+n],  n < 3072
__global__ __launch_bounds__(256)
void biasfold(const float* __restrict__ W, const float* __restrict__ bvec, float* __restrict__ outb)
{
  int n = blockIdx.x*256 + threadIdx.x;
  float s = 0.f;
  for (int k=0;k<1152;k++) s += bvec[k]*W[(long)k*3072 + n];
  outb[n] = s;
}

// fp32 -> bf16 elementwise (n multiple of 4)
__global__ __launch_bounds__(256)
void cvt_bf16x4(const float* __restrict__ in, short* __restrict__ o, long n)
{
  long i = ((long)blockIdx.x*256 + threadIdx.x)*4;
  if (i >= n) return;
  float4 v = *(const float4*)(in + i);
  o[i+0]=f2bf(v.x); o[i+1]=f2bf(v.y); o[i+2]=f2bf(v.z); o[i+3]=f2bf(v.w);
}

// latents broadcast into lat rows [b*128 .. b*128+63]
__global__ __launch_bounds__(256)
void latcopy(const float* __restrict__ latents, float* __restrict__ lat)
{
  int idx = blockIdx.x*256 + threadIdx.x;   // 32*64*1152 total, grid exact
  int d = idx % 1152; int j = (idx / 1152) % 64; int b = idx / (1152*64);
  lat[((long)b*128 + j)*1152 + d] = latents[j*1152 + d];
}

// V transpose per batch: Vt[(b*1536 + c)*864 + r] = kv[(b*857+r)*3072 + 1536 + c], r>=857 -> 0
__global__ __launch_bounds__(256)
void transV(const short* __restrict__ kv, short* __restrict__ Vt)
{
  int b = blockIdx.z;
  __shared__ short tile[32][33];
  int rb = blockIdx.y*32, cb = blockIdx.x*32;
  int tx = threadIdx.x & 31, ty = threadIdx.x >> 5;
  for (int i=ty; i<32; i+=8){
    int r = rb+i, c = cb+tx;
    short v = 0;
    if (r < 857) v = kv[((long)b*857 + r)*3072 + 1536 + c];
    tile[i][tx] = v;
  }
  __syncthreads();
  for (int i=ty;i<32;i+=8){
    int c = cb+i, r = rb+tx;
    Vt[((long)b*1536 + c)*864 + r] = tile[tx][i];
  }
}

// in-place row softmax over 857 valid cols of an 896-wide bf16 row; zero-pads cols 857..863
__global__ __launch_bounds__(256)
void softmax_rows(short* __restrict__ SP)
{
  long row = (long)blockIdx.x*4 + (threadIdx.x >> 6);
  int lane = threadIdx.x & 63;
  short* p = SP + row*896;
  float vals[14];
  float mx = -1e30f;
#pragma unroll
  for (int i=0;i<14;i++){
    int j = i*64 + lane;
    float v = (j < 857) ? bf2f(p[j]) : -1e30f;
    vals[i] = v; mx = fmaxf(mx, v);
  }
#pragma unroll
  for (int o=32;o;o>>=1) mx = fmaxf(mx, __shfl_xor(mx, o));
  float s = 0.f;
#pragma unroll
  for (int i=0;i<14;i++){
    int j = i*64 + lane;
    float e = (j < 857) ? __expf(vals[i]-mx) : 0.f;
    vals[i] = e; s += e;
  }
#pragma unroll
  for (int o=32;o;o>>=1) s += __shfl_xor(s, o);
  float inv = 1.0f / s;
#pragma unroll
  for (int i=0;i<14;i++){
    int j = i*64 + lane;
    if (j < 864) p[j] = f2bf(j < 857 ? vals[i]*inv : 0.f);
  }
}

// row LayerNorm, D=1152. inRow = (r/grpSel)*grpStride + r%grpSel. out row = r.
template<int OUTF32>
__global__ __launch_bounds__(256)
void ln_k(const float* __restrict__ in, void* __restrict__ outp,
          const float* __restrict__ w, const float* __restrict__ b,
          int grpSel, int grpStride)
{
  const int D = 1152;
  int r = blockIdx.x;
  long ir = (long)(r / grpSel)*grpStride + (r % grpSel);
  const float* x = in + ir*D;
  int tid = threadIdx.x;
  float s1=0.f, s2=0.f;
  float xv[5];
#pragma unroll
  for (int t=0;t<5;t++){
    int i = tid + t*256;
    xv[t] = (i < D) ? x[i] : 0.f;
    s1 += xv[t]; s2 += xv[t]*xv[t];
  }
#pragma unroll
  for (int o=32;o;o>>=1){ s1 += __shfl_xor(s1,o); s2 += __shfl_xor(s2,o); }
  __shared__ float red[8];
  int wid = tid>>6, lane = tid&63;
  if (lane==0){ red[wid]=s1; red[4+wid]=s2; }
  __syncthreads();
  s1 = red[0]+red[1]+red[2]+red[3];
  s2 = red[4]+red[5]+red[6]+red[7];
  float mu = s1 / D;
  float var = s2 / D - mu*mu;
  float rs = rsqrtf(var + 1e-5f);
#pragma unroll
  for (int t=0;t<5;t++){
    int i = tid + t*256;
    if (i >= D) break;
    float v = (xv[t]-mu)*rs;
    if (w) v = v*w[i] + b[i];
    if (OUTF32) ((float*)outp)[(long)r*D + i] = v;
    else        ((short*)outp)[(long)r*D + i] = f2bf(v);
  }
}

// ---------------------------------------------------------------------------

extern "C" void kernel_launch(void* const* d_in, const int* in_sizes, int n_in,
                              void* d_out, int out_size, void* d_ws, size_t ws_size,
                              hipStream_t stream)
{
  const float* x      = (const float*)d_in[0];   // (32,1,1,729,1152)
  const float* tein   = (const float*)d_in[1];   // (32,64,4096)
  const float* lat0   = (const float*)d_in[2];   // (64,1152)
  const float* txt_w1 = (const float*)d_in[3];
  const float* txt_b1 = (const float*)d_in[4];
  const float* txt_w2 = (const float*)d_in[5];
  const float* txt_b2 = (const float*)d_in[6];
  const float* nm_w   = (const float*)d_in[7];
  const float* nm_b   = (const float*)d_in[8];
  const float* nl_w   = (const float*)d_in[9];
  const float* nl_b   = (const float*)d_in[10];
  const float* Wq     = (const float*)d_in[11];
  const float* Wkv    = (const float*)d_in[12];
  const float* Wo     = (const float*)d_in[13];
  const float* ffln_w = (const float*)d_in[14];
  const float* ffln_b = (const float*)d_in[15];
  const float* ff_w1  = (const float*)d_in[16];
  const float* ff_w2  = (const float*)d_in[17];
  const float* oln_w  = (const float*)d_in[18];
  const float* oln_b  = (const float*)d_in[19];
  float* out = (float*)d_out;
  (void)in_sizes; (void)n_in; (void)out_size; (void)ws_size;

  const float SCALE = 0.1020620726159657f;  // 96^-0.5

  char* base = (char*)d_ws;
  size_t off = 0;
  auto alloc = [&](size_t bytes)->char*{
    char* r = base + off;
    off += (bytes + 255) & ~(size_t)255;
    return r;
  };
  short* wT    = (short*)alloc(4608ULL*1152*2);    // per-use transposed bf16 weight
  float* biasf = (float*)alloc(3072*4);            // folded kv bias
  short* xnorm = (short*)alloc(23328ULL*1152*2);   // pure-normalized x, bf16
  float* lat   = (float*)alloc(4096ULL*1152*4);    // residual stream fp32 (32 x 128 rows)
  short* lm    = (short*)alloc(4096ULL*1152*2);    // LN'd latents bf16
  short* qb    = (short*)alloc(4096ULL*1536*2);    // q bf16
  short* kv    = (short*)alloc(27424ULL*3072*2);   // (32*857, 3072) bf16
  short* Vt    = (short*)alloc(32ULL*1536*864*2);  // V transposed, zero-padded K
  short* SP    = (short*)alloc(65536ULL*896*2);    // scores / probs bf16 (in-place softmax)
  short* attn  = (short*)alloc(4096ULL*1536*2);    // attention out bf16
  short* ffh   = (short*)alloc(4096ULL*4608*2);    // FF hidden bf16
  short* txtin = SP;                               // alias (preamble only)
  short* txth  = SP + 2048ULL*4096;                // alias (preamble only)

  // ---- preamble: txt MLP -> lat rows 64..127; latents -> rows 0..63 ----
  cvt_bf16x4<<<8192,256,0,stream>>>(tein, txtin, 2048LL*4096);
  convT<<<dim3(36,128),256,0,stream>>>(txt_w1, wT, 4096, 1152, nullptr);
  gemm_t<1,1,0,0><<<dim3(9,16,1),256,0,stream>>>(txtin, wT, txth, txt_b1, nullptr,
      4096,4096,4096,1152, 2048,1152,1152, 1, 0,0,0,0,0,0, 1.f);
  convT<<<dim3(36,36),256,0,stream>>>(txt_w2, wT, 1152, 1152, nullptr);
  gemm_t<0,1,0,1><<<dim3(9,1,32),256,0,stream>>>(txth, wT, lat + 64*1152, txt_b2, nullptr,
      1152,1152,1152,1152, 64,1152,1152, 1, 64L*1152,0, 0,0, 128L*1152,0, 1.f);
  latcopy<<<9216,256,0,stream>>>(lat0, lat);

  // xnorm = pure LN(x) (affine folded into Wkv per layer)
  ln_k<0><<<23328,256,0,stream>>>(x, xnorm, nullptr, nullptr, 1<<28, 0);

  for (int L=0; L<6; L++){
    const float* WqL  = Wq    + (size_t)L*1152*1536;
    const float* WkvL = Wkv   + (size_t)L*1152*3072;
    const float* WoL  = Wo    + (size_t)L*1536*1152;
    const float* fw1  = ff_w1 + (size_t)L*1152*4608;
    const float* fw2  = ff_w2 + (size_t)L*4608*1152;

    // lm = LN(lat; nl)
    ln_k<0><<<4096,256,0,stream>>>(lat, lm, nl_w + L*1152, nl_b + L*1152, 1<<28, 0);

    // q = (lm @ Wq) * SCALE
    convT<<<dim3(48,36),256,0,stream>>>(WqL, wT, 1152, 1536, nullptr);
    gemm_t<0,0,0,0><<<dim3(12,32,1),256,0,stream>>>(lm, wT, qb, nullptr, nullptr,
        1152,1152,1152,1536, 4096,1536,1536, 1, 0,0,0,0,0,0, SCALE);

    // kv latent part: rows 729..856 per batch
    convT<<<dim3(96,36),256,0,stream>>>(WkvL, wT, 1152, 3072, nullptr);
    gemm_t<0,0,0,0><<<dim3(24,1,32),256,0,stream>>>(lm, wT, kv + 729L*3072, nullptr, nullptr,
        1152,1152,1152,3072, 128,3072,3072, 1, 128L*1152,0, 0,0, 857L*3072,0, 1.f);

    // kv x part (folded nm affine): rows 0..728 per batch
    convT<<<dim3(96,36),256,0,stream>>>(WkvL, wT, 1152, 3072, nm_w + L*1152);
    biasfold<<<12,256,0,stream>>>(WkvL, nm_b + L*1152, biasf);
    gemm_t<0,1,0,0><<<dim3(24,6,32),256,0,stream>>>(xnorm, wT, kv, biasf, nullptr,
        1152,1152,1152,3072, 729,3072,3072, 1, 729L*1152,0, 0,0, 857L*3072,0, 1.f);

    // Vt = V^T per batch, zero-padded to 864 keys
    transV<<<dim3(48,27,32),256,0,stream>>>(kv, Vt);

    // S = q . k^T  (batched over z = b*16+h)
    gemm_t<0,0,0,0><<<dim3(7,1,512),256,0,stream>>>(qb, kv, SP, nullptr, nullptr,
        96,1536,3072,896, 128,857,896, 16,
        128L*1536,96, 857L*3072,96, 16L*128*896,128L*896, 1.f);
    softmax_rows<<<16384,256,0,stream>>>(SP);
    // O = P . V   (Vt rows = output dims)
    gemm_t<0,0,0,0><<<dim3(1,1,512),256,0,stream>>>(SP, Vt, attn, nullptr, nullptr,
        864,896,864,1536, 128,96,96, 16,
        16L*128*896,128L*896, 1536L*864,96L*864, 128L*1536,96, 1.f);

    // lat += attn @ Wo
    convT<<<dim3(36,48),256,0,stream>>>(WoL, wT, 1536, 1152, nullptr);
    gemm_t<0,0,1,1><<<dim3(9,32,1),256,0,stream>>>(attn, wT, lat, nullptr, lat,
        1536,1536,1536,1152, 4096,1152,1152, 1, 0,0,0,0,0,0, 1.f);

    // FF: lat += gelu(LN(lat) @ w1) @ w2
    ln_k<0><<<4096,256,0,stream>>>(lat, lm, ffln_w + L*1152, ffln_b + L*1152, 1<<28, 0);
    convT<<<dim3(144,36),256,0,stream>>>(fw1, wT, 1152, 4608, nullptr);
    gemm_t<1,0,0,0><<<dim3(36,32,1),256,0,stream>>>(lm, wT, ffh, nullptr, nullptr,
        1152,1152,1152,4608, 4096,4608,4608, 1, 0,0,0,0,0,0, 1.f);
    convT<<<dim3(36,144),256,0,stream>>>(fw2, wT, 4608, 1152, nullptr);
    gemm_t<0,0,1,1><<<dim3(9,32,1),256,0,stream>>>(ffh, wT, lat, nullptr, lat,
        4608,4608,4608,1152, 4096,1152,1152, 1, 0,0,0,0,0,0, 1.f);
  }

  // final: out = LN(lat[:, :64, :]; out_ln)
  ln_k<1><<<2048,256,0,stream>>>(lat, out, oln_w, oln_b, 64, 128);
}

// Round 2
// 5823.923 us; speedup vs baseline: 1.0826x; 1.0826x over previous
//
#include <hip/hip_runtime.h>
#include <hip/hip_bf16.h>
#include <math.h>

// InstructPerceiverResampler on MI355X (gfx950).
// Round 2: gemm_t upgraded to double-buffered 2-phase prefetch (T3-min):
//   prologue stage(buf0); barrier;
//   loop: stage(buf^1, t+1) issued FIRST, then ds_read+MFMA on buf[cur],
//         then one __syncthreads per K-step.
// Everything else unchanged from round 1 (passed, absmax 0.031).
//
// Workspace layout (~503 MiB): wT | biasf | xnorm | lat | lm | q | kv | Vt | SP | attn | ffh

typedef __attribute__((ext_vector_type(4))) float f32x4;
typedef __attribute__((ext_vector_type(8))) short bf16x8;
typedef unsigned int u32;

#define DEV __device__ __forceinline__

DEV float bf2f(short s){ union{u32 u; float f;} v; v.u = ((u32)(unsigned short)s) << 16; return v.f; }
DEV short f2bf(float f){
  union{float f; u32 u;} v; v.f = f;
  u32 r = (v.u + 0x7FFFu + ((v.u >> 16) & 1u)) >> 16;
  return (short)r;
}

// ---------------------------------------------------------------------------
// Generic batched T-mode GEMM: C[m,n] = scale * sum_k A[m,k]*B[n,k] (+bias)(+gelu)(+res)
// A: bf16 row-major (lda), B: bf16 row-major N x K (ldb).
// Tile 128x128, BK=32, 256 threads (4 waves, 2x2 of 64x64), dbuf 2-phase.
// ---------------------------------------------------------------------------
template<int GELU, int BIAS, int RES, int OUTF32>
__global__ __launch_bounds__(256)
void gemm_t(const short* __restrict__ A, const short* __restrict__ B,
            void* __restrict__ C, const float* __restrict__ bias,
            const float* __restrict__ res,
            int K, int lda, int ldb, int ldc,
            int Mvalid, int NBmax, int Nwrite,
            int zdiv, long sA1, long sA2, long sB1, long sB2, long sC1, long sC2,
            float scale)
{
  __shared__ __align__(16) short As[2][128*32];
  __shared__ __align__(16) short Bs[2][128*32];

  int z = blockIdx.z;
  int zq = z / zdiv, zr = z - zq*zdiv;
  const short* Ab = A + zq*sA1 + zr*sA2;
  const short* Bb = B + zq*sB1 + zr*sB2;
  long cOff = zq*sC1 + zr*sC2;
  int m0 = blockIdx.y * 128;
  int n0 = blockIdx.x * 128;
  int tid = threadIdx.x;
  int lane = tid & 63;
  int w = tid >> 6;
  int wm = (w >> 1) * 64, wn = (w & 1) * 64;

  // staging: per wave, 2 chunks of 16 rows each for A and B. lane covers
  // row = base + lane/4, elem col = (lane&3)*8; hw writes lane at base+lane*16B.
  int sr = lane >> 2;
  int sc = (lane & 3) * 8;
  int ar0 = m0 + w*32 + sr;
  int br0 = n0 + w*32 + sr;

  // clamped global row bases (loop-invariant)
  int raA0 = ar0;      if (raA0 > Mvalid-1) raA0 = Mvalid-1;
  int raA1 = ar0 + 16; if (raA1 > Mvalid-1) raA1 = Mvalid-1;
  int rbB0 = br0;      if (rbB0 > NBmax-1) rbB0 = NBmax-1;
  int rbB1 = br0 + 16; if (rbB1 > NBmax-1) rbB1 = NBmax-1;
  const short* gA0 = Ab + (long)raA0*lda + sc;
  const short* gA1 = Ab + (long)raA1*lda + sc;
  const short* gB0 = Bb + (long)rbB0*ldb + sc;
  const short* gB1 = Bb + (long)rbB1*ldb + sc;
  int ldsRow0 = (w*32)*32;       // short index of this wave's chunk-0 base
  int ldsRow1 = (w*32 + 16)*32;

  f32x4 acc[4][4];
#pragma unroll
  for (int i=0;i<4;i++)
#pragma unroll
    for (int j=0;j<4;j++) acc[i][j] = (f32x4){0.f,0.f,0.f,0.f};

  auto stage = [&](int buf, int kb){
    __builtin_amdgcn_global_load_lds(
        (const __attribute__((address_space(1))) u32*)(gA0 + kb),
        (__attribute__((address_space(3))) u32*)(&As[buf][ldsRow0]), 16, 0, 0);
    __builtin_amdgcn_global_load_lds(
        (const __attribute__((address_space(1))) u32*)(gA1 + kb),
        (__attribute__((address_space(3))) u32*)(&As[buf][ldsRow1]), 16, 0, 0);
    __builtin_amdgcn_global_load_lds(
        (const __attribute__((address_space(1))) u32*)(gB0 + kb),
        (__attribute__((address_space(3))) u32*)(&Bs[buf][ldsRow0]), 16, 0, 0);
    __builtin_amdgcn_global_load_lds(
        (const __attribute__((address_space(1))) u32*)(gB1 + kb),
        (__attribute__((address_space(3))) u32*)(&Bs[buf][ldsRow1]), 16, 0, 0);
  };

  int nt = K >> 5;
  stage(0, 0);
  __syncthreads();

  int kq = (lane >> 4) * 8;
  int rsel = lane & 15;
  int cur = 0;
  for (int t = 0; t < nt; ++t){
    if (t + 1 < nt) stage(cur ^ 1, (t+1)*32);

    bf16x8 af[4], bfr[4];
#pragma unroll
    for (int m=0;m<4;m++) af[m]  = *(const bf16x8*)&As[cur][(wm + m*16 + rsel)*32 + kq];
#pragma unroll
    for (int n=0;n<4;n++) bfr[n] = *(const bf16x8*)&Bs[cur][(wn + n*16 + rsel)*32 + kq];
#pragma unroll
    for (int m=0;m<4;m++)
#pragma unroll
      for (int n=0;n<4;n++)
        acc[m][n] = __builtin_amdgcn_mfma_f32_16x16x32_bf16(af[m], bfr[n], acc[m][n], 0, 0, 0);

    __syncthreads();
    cur ^= 1;
  }

  // epilogue: C/D layout col=lane&15, row=(lane>>4)*4+j (m89-verified)
  int cq = (lane >> 4) * 4;
  int csel = lane & 15;
#pragma unroll
  for (int m=0;m<4;m++){
#pragma unroll
    for (int n=0;n<4;n++){
#pragma unroll
      for (int j=0;j<4;j++){
        int gm = m0 + wm + m*16 + cq + j;
        int gn = n0 + wn + n*16 + csel;
        if (gm < Mvalid && gn < Nwrite){
          float v = acc[m][n][j] * scale;
          if (BIAS) v += bias[gn];
          if (GELU) v = 0.5f*v*(1.0f + erff(v*0.70710678118654752f));
          long off = cOff + (long)gm*ldc + gn;
          if (OUTF32){
            float rv = RES ? res[off] : 0.0f;
            ((float*)C)[off] = v + rv;
          } else {
            ((short*)C)[off] = f2bf(v);
          }
        }
      }
    }
  }
}

// ---------------------------------------------------------------------------
// transpose-convert: out[n*K+k] = bf16(in[k*N+n] * (s ? s[k] : 1))
// ---------------------------------------------------------------------------
__global__ __launch_bounds__(256)
void convT(const float* __restrict__ in, short* __restrict__ out,
           int K, int N, const float* __restrict__ s)
{
  __shared__ float tile[32][33];
  int kb = blockIdx.y*32, nb = blockIdx.x*32;
  int tx = threadIdx.x & 31, ty = threadIdx.x >> 5;
  for (int i = ty; i < 32; i += 8){
    int k = kb + i, n = nb + tx;
    float v = 0.f;
    if (k < K && n < N){ v = in[(long)k*N + n]; if (s) v *= s[k]; }
    tile[i][tx] = v;
  }
  __syncthreads();
  for (int i = ty; i < 32; i += 8){
    int n = nb + i, k = kb + tx;
    if (n < N && k < K) out[(long)n*K + k] = f2bf(tile[tx][i]);
  }
}

// biasf[n] = sum_k bvec[k] * W[k*3072+n],  n < 3072
__global__ __launch_bounds__(256)
void biasfold(const float* __restrict__ W, const float* __restrict__ bvec, float* __restrict__ outb)
{
  int n = blockIdx.x*256 + threadIdx.x;
  float s = 0.f;
  for (int k=0;k<1152;k++) s += bvec[k]*W[(long)k*3072 + n];
  outb[n] = s;
}

// fp32 -> bf16 elementwise (n multiple of 4)
__global__ __launch_bounds__(256)
void cvt_bf16x4(const float* __restrict__ in, short* __restrict__ o, long n)
{
  long i = ((long)blockIdx.x*256 + threadIdx.x)*4;
  if (i >= n) return;
  float4 v = *(const float4*)(in + i);
  o[i+0]=f2bf(v.x); o[i+1]=f2bf(v.y); o[i+2]=f2bf(v.z); o[i+3]=f2bf(v.w);
}

// latents broadcast into lat rows [b*128 .. b*128+63]
__global__ __launch_bounds__(256)
void latcopy(const float* __restrict__ latents, float* __restrict__ lat)
{
  int idx = blockIdx.x*256 + threadIdx.x;   // 32*64*1152 total, grid exact
  int d = idx % 1152; int j = (idx / 1152) % 64; int b = idx / (1152*64);
  lat[((long)b*128 + j)*1152 + d] = latents[j*1152 + d];
}

// V transpose per batch: Vt[(b*1536 + c)*864 + r] = kv[(b*857+r)*3072 + 1536 + c], r>=857 -> 0
__global__ __launch_bounds__(256)
void transV(const short* __restrict__ kv, short* __restrict__ Vt)
{
  int b = blockIdx.z;
  __shared__ short tile[32][33];
  int rb = blockIdx.y*32, cb = blockIdx.x*32;
  int tx = threadIdx.x & 31, ty = threadIdx.x >> 5;
  for (int i=ty; i<32; i+=8){
    int r = rb+i, c = cb+tx;
    short v = 0;
    if (r < 857) v = kv[((long)b*857 + r)*3072 + 1536 + c];
    tile[i][tx] = v;
  }
  __syncthreads();
  for (int i=ty;i<32;i+=8){
    int c = cb+i, r = rb+tx;
    Vt[((long)b*1536 + c)*864 + r] = tile[tx][i];
  }
}

// in-place row softmax over 857 valid cols of an 896-wide bf16 row; zero-pads cols 857..863
__global__ __launch_bounds__(256)
void softmax_rows(short* __restrict__ SP)
{
  long row = (long)blockIdx.x*4 + (threadIdx.x >> 6);
  int lane = threadIdx.x & 63;
  short* p = SP + row*896;
  float vals[14];
  float mx = -1e30f;
#pragma unroll
  for (int i=0;i<14;i++){
    int j = i*64 + lane;
    float v = (j < 857) ? bf2f(p[j]) : -1e30f;
    vals[i] = v; mx = fmaxf(mx, v);
  }
#pragma unroll
  for (int o=32;o;o>>=1) mx = fmaxf(mx, __shfl_xor(mx, o));
  float s = 0.f;
#pragma unroll
  for (int i=0;i<14;i++){
    int j = i*64 + lane;
    float e = (j < 857) ? __expf(vals[i]-mx) : 0.f;
    vals[i] = e; s += e;
  }
#pragma unroll
  for (int o=32;o;o>>=1) s += __shfl_xor(s, o);
  float inv = 1.0f / s;
#pragma unroll
  for (int i=0;i<14;i++){
    int j = i*64 + lane;
    if (j < 864) p[j] = f2bf(j < 857 ? vals[i]*inv : 0.f);
  }
}

// row LayerNorm, D=1152. inRow = (r/grpSel)*grpStride + r%grpSel. out row = r.
template<int OUTF32>
__global__ __launch_bounds__(256)
void ln_k(const float* __restrict__ in, void* __restrict__ outp,
          const float* __restrict__ w, const float* __restrict__ b,
          int grpSel, int grpStride)
{
  const int D = 1152;
  int r = blockIdx.x;
  long ir = (long)(r / grpSel)*grpStride + (r % grpSel);
  const float* x = in + ir*D;
  int tid = threadIdx.x;
  float s1=0.f, s2=0.f;
  float xv[5];
#pragma unroll
  for (int t=0;t<5;t++){
    int i = tid + t*256;
    xv[t] = (i < D) ? x[i] : 0.f;
    s1 += xv[t]; s2 += xv[t]*xv[t];
  }
#pragma unroll
  for (int o=32;o;o>>=1){ s1 += __shfl_xor(s1,o); s2 += __shfl_xor(s2,o); }
  __shared__ float red[8];
  int wid = tid>>6, lane = tid&63;
  if (lane==0){ red[wid]=s1; red[4+wid]=s2; }
  __syncthreads();
  s1 = red[0]+red[1]+red[2]+red[3];
  s2 = red[4]+red[5]+red[6]+red[7];
  float mu = s1 / D;
  float var = s2 / D - mu*mu;
  float rs = rsqrtf(var + 1e-5f);
#pragma unroll
  for (int t=0;t<5;t++){
    int i = tid + t*256;
    if (i >= D) break;
    float v = (xv[t]-mu)*rs;
    if (w) v = v*w[i] + b[i];
    if (OUTF32) ((float*)outp)[(long)r*D + i] = v;
    else        ((short*)outp)[(long)r*D + i] = f2bf(v);
  }
}

// ---------------------------------------------------------------------------

extern "C" void kernel_launch(void* const* d_in, const int* in_sizes, int n_in,
                              void* d_out, int out_size, void* d_ws, size_t ws_size,
                              hipStream_t stream)
{
  const float* x      = (const float*)d_in[0];   // (32,1,1,729,1152)
  const float* tein   = (const float*)d_in[1];   // (32,64,4096)
  const float* lat0   = (const float*)d_in[2];   // (64,1152)
  const float* txt_w1 = (const float*)d_in[3];
  const float* txt_b1 = (const float*)d_in[4];
  const float* txt_w2 = (const float*)d_in[5];
  const float* txt_b2 = (const float*)d_in[6];
  const float* nm_w   = (const float*)d_in[7];
  const float* nm_b   = (const float*)d_in[8];
  const float* nl_w   = (const float*)d_in[9];
  const float* nl_b   = (const float*)d_in[10];
  const float* Wq     = (const float*)d_in[11];
  const float* Wkv    = (const float*)d_in[12];
  const float* Wo     = (const float*)d_in[13];
  const float* ffln_w = (const float*)d_in[14];
  const float* ffln_b = (const float*)d_in[15];
  const float* ff_w1  = (const float*)d_in[16];
  const float* ff_w2  = (const float*)d_in[17];
  const float* oln_w  = (const float*)d_in[18];
  const float* oln_b  = (const float*)d_in[19];
  float* out = (float*)d_out;
  (void)in_sizes; (void)n_in; (void)out_size; (void)ws_size;

  const float SCALE = 0.1020620726159657f;  // 96^-0.5

  char* base = (char*)d_ws;
  size_t off = 0;
  auto alloc = [&](size_t bytes)->char*{
    char* r = base + off;
    off += (bytes + 255) & ~(size_t)255;
    return r;
  };
  short* wT    = (short*)alloc(4608ULL*1152*2);    // per-use transposed bf16 weight
  float* biasf = (float*)alloc(3072*4);            // folded kv bias
  short* xnorm = (short*)alloc(23328ULL*1152*2);   // pure-normalized x, bf16
  float* lat   = (float*)alloc(4096ULL*1152*4);    // residual stream fp32 (32 x 128 rows)
  short* lm    = (short*)alloc(4096ULL*1152*2);    // LN'd latents bf16
  short* qb    = (short*)alloc(4096ULL*1536*2);    // q bf16
  short* kv    = (short*)alloc(27424ULL*3072*2);   // (32*857, 3072) bf16
  short* Vt    = (short*)alloc(32ULL*1536*864*2);  // V transposed, zero-padded K
  short* SP    = (short*)alloc(65536ULL*896*2);    // scores / probs bf16 (in-place softmax)
  short* attn  = (short*)alloc(4096ULL*1536*2);    // attention out bf16
  short* ffh   = (short*)alloc(4096ULL*4608*2);    // FF hidden bf16
  short* txtin = SP;                               // alias (preamble only)
  short* txth  = SP + 2048ULL*4096;                // alias (preamble only)

  // ---- preamble: txt MLP -> lat rows 64..127; latents -> rows 0..63 ----
  cvt_bf16x4<<<8192,256,0,stream>>>(tein, txtin, 2048LL*4096);
  convT<<<dim3(36,128),256,0,stream>>>(txt_w1, wT, 4096, 1152, nullptr);
  gemm_t<1,1,0,0><<<dim3(9,16,1),256,0,stream>>>(txtin, wT, txth, txt_b1, nullptr,
      4096,4096,4096,1152, 2048,1152,1152, 1, 0,0,0,0,0,0, 1.f);
  convT<<<dim3(36,36),256,0,stream>>>(txt_w2, wT, 1152, 1152, nullptr);
  gemm_t<0,1,0,1><<<dim3(9,1,32),256,0,stream>>>(txth, wT, lat + 64*1152, txt_b2, nullptr,
      1152,1152,1152,1152, 64,1152,1152, 1, 64L*1152,0, 0,0, 128L*1152,0, 1.f);
  latcopy<<<9216,256,0,stream>>>(lat0, lat);

  // xnorm = pure LN(x) (affine folded into Wkv per layer)
  ln_k<0><<<23328,256,0,stream>>>(x, xnorm, nullptr, nullptr, 1<<28, 0);

  for (int L=0; L<6; L++){
    const float* WqL  = Wq    + (size_t)L*1152*1536;
    const float* WkvL = Wkv   + (size_t)L*1152*3072;
    const float* WoL  = Wo    + (size_t)L*1536*1152;
    const float* fw1  = ff_w1 + (size_t)L*1152*4608;
    const float* fw2  = ff_w2 + (size_t)L*4608*1152;

    // lm = LN(lat; nl)
    ln_k<0><<<4096,256,0,stream>>>(lat, lm, nl_w + L*1152, nl_b + L*1152, 1<<28, 0);

    // q = (lm @ Wq) * SCALE
    convT<<<dim3(48,36),256,0,stream>>>(WqL, wT, 1152, 1536, nullptr);
    gemm_t<0,0,0,0><<<dim3(12,32,1),256,0,stream>>>(lm, wT, qb, nullptr, nullptr,
        1152,1152,1152,1536, 4096,1536,1536, 1, 0,0,0,0,0,0, SCALE);

    // kv latent part: rows 729..856 per batch
    convT<<<dim3(96,36),256,0,stream>>>(WkvL, wT, 1152, 3072, nullptr);
    gemm_t<0,0,0,0><<<dim3(24,1,32),256,0,stream>>>(lm, wT, kv + 729L*3072, nullptr, nullptr,
        1152,1152,1152,3072, 128,3072,3072, 1, 128L*1152,0, 0,0, 857L*3072,0, 1.f);

    // kv x part (folded nm affine): rows 0..728 per batch
    convT<<<dim3(96,36),256,0,stream>>>(WkvL, wT, 1152, 3072, nm_w + L*1152);
    biasfold<<<12,256,0,stream>>>(WkvL, nm_b + L*1152, biasf);
    gemm_t<0,1,0,0><<<dim3(24,6,32),256,0,stream>>>(xnorm, wT, kv, biasf, nullptr,
        1152,1152,1152,3072, 729,3072,3072, 1, 729L*1152,0, 0,0, 857L*3072,0, 1.f);

    // Vt = V^T per batch, zero-padded to 864 keys
    transV<<<dim3(48,27,32),256,0,stream>>>(kv, Vt);

    // S = q . k^T  (batched over z = b*16+h)
    gemm_t<0,0,0,0><<<dim3(7,1,512),256,0,stream>>>(qb, kv, SP, nullptr, nullptr,
        96,1536,3072,896, 128,857,896, 16,
        128L*1536,96, 857L*3072,96, 16L*128*896,128L*896, 1.f);
    softmax_rows<<<16384,256,0,stream>>>(SP);
    // O = P . V   (Vt rows = output dims)
    gemm_t<0,0,0,0><<<dim3(1,1,512),256,0,stream>>>(SP, Vt, attn, nullptr, nullptr,
        864,896,864,1536, 128,96,96, 16,
        16L*128*896,128L*896, 1536L*864,96L*864, 128L*1536,96, 1.f);

    // lat += attn @ Wo
    convT<<<dim3(36,48),256,0,stream>>>(WoL, wT, 1536, 1152, nullptr);
    gemm_t<0,0,1,1><<<dim3(9,32,1),256,0,stream>>>(attn, wT, lat, nullptr, lat,
        1536,1536,1536,1152, 4096,1152,1152, 1, 0,0,0,0,0,0, 1.f);

    // FF: lat += gelu(LN(lat) @ w1) @ w2
    ln_k<0><<<4096,256,0,stream>>>(lat, lm, ffln_w + L*1152, ffln_b + L*1152, 1<<28, 0);
    convT<<<dim3(144,36),256,0,stream>>>(fw1, wT, 1152, 4608, nullptr);
    gemm_t<1,0,0,0><<<dim3(36,32,1),256,0,stream>>>(lm, wT, ffh, nullptr, nullptr,
        1152,1152,1152,4608, 4096,4608,4608, 1, 0,0,0,0,0,0, 1.f);
    convT<<<dim3(36,144),256,0,stream>>>(fw2, wT, 4608, 1152, nullptr);
    gemm_t<0,0,1,1><<<dim3(9,32,1),256,0,stream>>>(ffh, wT, lat, nullptr, lat,
        4608,4608,4608,1152, 4096,1152,1152, 1, 0,0,0,0,0,0, 1.f);
  }

  // final: out = LN(lat[:, :64, :]; out_ln)
  ln_k<1><<<2048,256,0,stream>>>(lat, out, oln_w, oln_b, 64, 128);
}